// Round 1
// baseline (886.399 us; speedup 1.0000x reference)
//
#include <hip/hip_runtime.h>
#include <hip/hip_bf16.h>
#include <stdint.h>

// Problem constants (from reference)
#define M_TOT 4096   // 2 * 2048
#define K_DIM 4096   // IN_FEATURES
#define N_DIM 16384  // OUT_FEATURES

// GEMM tiling (m97 structure: 128x128 tile, BK=32, 4 waves 2x2, 4x4 frags/wave)
#define BM 128
#define BN 128
#define BK 32

typedef __attribute__((ext_vector_type(8))) short bf16x8;  // 8 bf16 = 4 VGPRs
typedef __attribute__((ext_vector_type(4))) float f32x4;   // MFMA 16x16 acc

__device__ __forceinline__ unsigned short f2bf(float f) {
  union { float f; unsigned u; } v; v.f = f;
  unsigned r = v.u + 0x7fffu + ((v.u >> 16) & 1u);  // RNE
  return (unsigned short)(r >> 16);
}

// fp32 -> bf16, 4 elems/thread/iter
__global__ void cvt_f32_bf16_k(const float4* __restrict__ src,
                               ushort4* __restrict__ dst, int n4) {
  int stride = gridDim.x * blockDim.x;
  for (int i = blockIdx.x * blockDim.x + threadIdx.x; i < n4; i += stride) {
    float4 v = src[i];
    ushort4 o;
    o.x = f2bf(v.x); o.y = f2bf(v.y); o.z = f2bf(v.z); o.w = f2bf(v.w);
    dst[i] = o;
  }
}

// int32 (in [-7,7], exact in bf16) -> bf16
__global__ void cvt_i32_bf16_k(const int4* __restrict__ src,
                               ushort4* __restrict__ dst, int n4) {
  int stride = gridDim.x * blockDim.x;
  for (int i = blockIdx.x * blockDim.x + threadIdx.x; i < n4; i += stride) {
    int4 v = src[i];
    ushort4 o;
    o.x = f2bf((float)v.x); o.y = f2bf((float)v.y);
    o.z = f2bf((float)v.z); o.w = f2bf((float)v.w);
    dst[i] = o;
  }
}

// async global->LDS, 16B per lane, LDS dest must be wave-uniform base
__device__ __forceinline__ void gload16(const void* g, void* l) {
  __builtin_amdgcn_global_load_lds(
      (__attribute__((address_space(1))) void*)(g),
      (__attribute__((address_space(3))) void*)(l),
      16, 0, 0);
}

// C = A(MxK) * W(NxK)^T, then C[m][n] = C*scale[n] + bias[n]
// A, W are bf16 row-major. 256 threads, 4 waves (2x2), each wave 64x64.
__global__ __launch_bounds__(256)
void gemm_bt_scaled(const ushort* __restrict__ A, const ushort* __restrict__ W,
                    const float* __restrict__ scale, const float* __restrict__ bias,
                    float* __restrict__ C) {
  __shared__ __align__(16) ushort As[BM * BK];  // 8 KB
  __shared__ __align__(16) ushort Bs[BN * BK];  // 8 KB

  const int tid  = threadIdx.x;
  const int lane = tid & 63;
  const int wave = tid >> 6;
  const int wm   = wave >> 1;   // 0..1 (row of wave grid)
  const int wn   = wave & 1;    // 0..1 (col of wave grid)

  // XCD-aware bijective swizzle (nwg = 4096, divisible by 8)
  const int nwg  = gridDim.x;
  const int bid  = blockIdx.x;
  const int cpx  = nwg >> 3;
  const int wgid = (bid & 7) * cpx + (bid >> 3);
  const int ntn  = N_DIM / BN;           // 128
  const int tm   = wgid / ntn;
  const int tn   = wgid % ntn;
  const int row0 = tm * BM;
  const int col0 = tn * BN;

  // Staging: thread t covers row (t>>2), 8 bf16 at col (t&3)*8 of the 128x32 tile.
  // Two call-sites per operand cover rows 0..63 / 64..127.
  const int sr = tid >> 2;            // 0..63
  const int sc = (tid & 3) * 8;       // 0,8,16,24
  const ushort* gA0 = A + (size_t)(row0 + sr) * K_DIM + sc;
  const ushort* gA1 = gA0 + (size_t)64 * K_DIM;
  const ushort* gB0 = W + (size_t)(col0 + sr) * K_DIM + sc;
  const ushort* gB1 = gB0 + (size_t)64 * K_DIM;

  // wave-uniform LDS bases: wave w writes bytes [w*1024, w*1024+1024) of each 4KB site
  ushort* lA0 = &As[wave * 512];
  ushort* lA1 = lA0 + 2048;
  ushort* lB0 = &Bs[wave * 512];
  ushort* lB1 = lB0 + 2048;

  f32x4 acc[4][4];
#pragma unroll
  for (int i = 0; i < 4; ++i)
#pragma unroll
    for (int j = 0; j < 4; ++j)
      acc[i][j] = (f32x4){0.f, 0.f, 0.f, 0.f};

  // Fragment read pattern (identical for A and B since W is [N][K]):
  // lane holds T[16-row-group + (lane&15)][(lane>>4)*8 .. +8]
  const int r  = lane & 15;
  const int kq = lane >> 4;
  const ushort* rA = &As[(wm * 64 + r) * BK + kq * 8];
  const ushort* rB = &Bs[(wn * 64 + r) * BK + kq * 8];

  for (int k0 = 0; k0 < K_DIM; k0 += BK) {
    __syncthreads();  // all waves done reading LDS from previous step
    gload16(gA0 + k0, lA0);
    gload16(gA1 + k0, lA1);
    gload16(gB0 + k0, lB0);
    gload16(gB1 + k0, lB1);
    __syncthreads();  // drains vmcnt: staged tiles visible

    bf16x8 a[4], b[4];
#pragma unroll
    for (int mi = 0; mi < 4; ++mi)
      a[mi] = *(const bf16x8*)(rA + mi * 16 * BK);
#pragma unroll
    for (int ni = 0; ni < 4; ++ni)
      b[ni] = *(const bf16x8*)(rB + ni * 16 * BK);
#pragma unroll
    for (int mi = 0; mi < 4; ++mi)
#pragma unroll
      for (int ni = 0; ni < 4; ++ni)
        acc[mi][ni] = __builtin_amdgcn_mfma_f32_16x16x32_bf16(
            a[mi], b[ni], acc[mi][ni], 0, 0, 0);
  }

  // Epilogue: C/D layout col=lane&15, row=(lane>>4)*4+reg (m89-verified)
#pragma unroll
  for (int ni = 0; ni < 4; ++ni) {
    const int col = col0 + wn * 64 + ni * 16 + r;
    const float s = scale[col];
    const float bv = bias[col];
#pragma unroll
    for (int mi = 0; mi < 4; ++mi) {
      const int rowb = row0 + wm * 64 + mi * 16 + kq * 4;
#pragma unroll
      for (int q = 0; q < 4; ++q) {
        C[(size_t)(rowb + q) * N_DIM + col] = acc[mi][ni][q] * s + bv;
      }
    }
  }
}

extern "C" void kernel_launch(void* const* d_in, const int* in_sizes, int n_in,
                              void* d_out, int out_size, void* d_ws, size_t ws_size,
                              hipStream_t stream) {
  const float* x      = (const float*)d_in[0];  // [2,2048,4096] f32
  const int*   wq     = (const int*)d_in[1];    // [16384,4096] i32 in [-7,7]
  const float* wscale = (const float*)d_in[2];  // [16384]
  const float* wbias  = (const float*)d_in[3];  // [16384]
  float* out = (float*)d_out;                   // [2,2048,16384] f32

  const size_t xb_bytes = (size_t)M_TOT * K_DIM * 2;   // 32 MB
  const size_t wb_bytes = (size_t)N_DIM * K_DIM * 2;   // 128 MB
  if (ws_size < xb_bytes + wb_bytes) return;  // visible-fail guard (ws too small)

  ushort* xb = (ushort*)d_ws;
  ushort* wb = (ushort*)((char*)d_ws + xb_bytes);

  cvt_f32_bf16_k<<<2048, 256, 0, stream>>>((const float4*)x, (ushort4*)xb,
                                           (M_TOT * K_DIM) / 4);
  cvt_i32_bf16_k<<<2048, 256, 0, stream>>>((const int4*)wq, (ushort4*)wb,
                                           (N_DIM * K_DIM) / 4);

  const int grid = (M_TOT / BM) * (N_DIM / BN);  // 32 * 128 = 4096
  gemm_bt_scaled<<<grid, 256, 0, stream>>>(xb, wb, wscale, wbias, out);
}

// Round 2
// 640.478 us; speedup vs baseline: 1.3840x; 1.3840x over previous
//
#include <hip/hip_runtime.h>
#include <hip/hip_bf16.h>
#include <stdint.h>

// Problem constants
#define M_TOT 4096   // 2 * 2048
#define K_DIM 4096   // IN_FEATURES
#define N_DIM 16384  // OUT_FEATURES

typedef __attribute__((ext_vector_type(8))) short bf16x8;  // 8 bf16 = 4 VGPRs
typedef __attribute__((ext_vector_type(4))) float f32x4;   // MFMA 16x16 acc

__device__ __forceinline__ unsigned short f2bf(float f) {
  union { float f; unsigned u; } v; v.f = f;
  unsigned r = v.u + 0x7fffu + ((v.u >> 16) & 1u);  // RNE
  return (unsigned short)(r >> 16);
}

__global__ void cvt_f32_bf16_k(const float4* __restrict__ src,
                               ushort4* __restrict__ dst, int n4) {
  int stride = gridDim.x * blockDim.x;
  for (int i = blockIdx.x * blockDim.x + threadIdx.x; i < n4; i += stride) {
    float4 v = src[i];
    ushort4 o;
    o.x = f2bf(v.x); o.y = f2bf(v.y); o.z = f2bf(v.z); o.w = f2bf(v.w);
    dst[i] = o;
  }
}

__global__ void cvt_i32_bf16_k(const int4* __restrict__ src,
                               ushort4* __restrict__ dst, int n4) {
  int stride = gridDim.x * blockDim.x;
  for (int i = blockIdx.x * blockDim.x + threadIdx.x; i < n4; i += stride) {
    int4 v = src[i];
    ushort4 o;
    o.x = f2bf((float)v.x); o.y = f2bf((float)v.y);
    o.z = f2bf((float)v.z); o.w = f2bf((float)v.w);
    dst[i] = o;
  }
}

__device__ __forceinline__ void gload16(const void* g, void* l) {
  __builtin_amdgcn_global_load_lds(
      (__attribute__((address_space(1))) void*)(g),
      (__attribute__((address_space(3))) void*)(l),
      16, 0, 0);
}

// XOR-swizzle involution on byte offsets within a 16KB block ([256][32] bf16,
// 64B rows). XORs bits 4-6 with bits 7-9 ((row>>1)&7): bits 7-9 untouched ->
// involution. Spreads 16 fragment rows over 8 x 16B slots (2-way = free).
#define SWZ(o) ((o) ^ ((((o) >> 7) & 7) << 4))

#define MFMA_B16(a, b, c) __builtin_amdgcn_mfma_f32_16x16x32_bf16(a, b, c, 0, 0, 0)

// 256x256 tile, BK=64, 8 waves (2M x 4N), 8-phase schedule (2 K-tiles / 8 phases),
// counted vmcnt(4), setprio around MFMA, XOR-swizzled LDS.
// LDS (bytes): buf b at b*65536; A slice s at +s*16384; B slice s at +32768+s*16384.
__global__ __launch_bounds__(512, 2)
void gemm_8phase(const ushort* __restrict__ A, const ushort* __restrict__ W,
                 const float* __restrict__ scale, const float* __restrict__ bias,
                 float* __restrict__ C) {
  __shared__ __align__(16) ushort lds[65536];  // 128 KiB
  char* lbase = (char*)lds;

  const int tid  = threadIdx.x;
  const int lane = tid & 63;
  const int wave = tid >> 6;
  const int wm   = wave >> 2;  // 0..1
  const int wn   = wave & 3;   // 0..3
  const int r    = lane & 15;
  const int kq16 = (lane >> 4) << 4;  // kq*16 bytes

  // XCD-bijective swizzle (nwg = 1024, divisible by 8)
  const int nwg  = gridDim.x;
  const int bid  = blockIdx.x;
  const int wgid = (bid & 7) * (nwg >> 3) + (bid >> 3);
  const int tm   = wgid >> 6;   // N_DIM/256 = 64 tiles per row
  const int tn   = wgid & 63;
  const int row0 = tm * 256;
  const int col0 = tn * 256;

  // Staging: per-thread global source coords for the 2 issues per 16KB block.
  // Linear LDS dest off = j*8192 + tid*16; it must hold logical SWZ(off).
  int s_row0, s_col0, s_row1, s_col1;
  {
    int l0 = SWZ(tid * 16);
    int l1 = SWZ(8192 + tid * 16);
    s_row0 = l0 >> 6; s_col0 = (l0 & 63) >> 1;
    s_row1 = l1 >> 6; s_col1 = (l1 & 63) >> 1;
  }

  auto STAGE = [&](const ushort* G, int rb, int kb, int blkB) {
    gload16(G + (size_t)(rb + s_row0) * K_DIM + kb + s_col0,
            lbase + blkB + (wave << 10));
    gload16(G + (size_t)(rb + s_row1) * K_DIM + kb + s_col1,
            lbase + blkB + 8192 + (wave << 10));
  };

  f32x4 acc[8][4];
#pragma unroll
  for (int i = 0; i < 8; ++i)
#pragma unroll
    for (int j = 0; j < 4; ++j)
      acc[i][j] = (f32x4){0.f, 0.f, 0.f, 0.f};

  // Prologue: T0 all 4 blocks + T1 slice-0 blocks (6 stages = 12 loads/thread)
  STAGE(A, row0, 0,  0);
  STAGE(W, col0, 0,  32768);
  STAGE(A, row0, 32, 16384);
  STAGE(W, col0, 32, 49152);
  STAGE(A, row0, 64, 65536);
  STAGE(W, col0, 64, 98304);
  asm volatile("s_waitcnt vmcnt(4)" ::: "memory");  // T0 resident, T1-s0 in flight
  __builtin_amdgcn_s_barrier();

  bf16x8 a[4], b[4];

  for (int t = 0; t < 64; ++t) {
    const int cur  = t & 1;
    const int curB = cur << 16;
    const int nxtB = (cur ^ 1) << 16;
    const int t1   = (t + 1 < 64) ? t + 1 : 63;  // clamp keeps vmcnt uniform
    const int t2   = (t + 2 < 64) ? t + 2 : 63;

    // ---- phase 1: m-half 0, k-slice 0 ----
#pragma unroll
    for (int i = 0; i < 4; ++i)
      a[i] = *(const bf16x8*)(lbase + curB + SWZ(((wm * 128 + i * 16 + r) << 6) + kq16));
#pragma unroll
    for (int i = 0; i < 4; ++i)
      b[i] = *(const bf16x8*)(lbase + curB + 32768 + SWZ(((wn * 64 + i * 16 + r) << 6) + kq16));
    STAGE(A, row0, t1 * 64 + 32, nxtB + 16384);  // T(t+1) A s1
    __builtin_amdgcn_s_barrier();
    __builtin_amdgcn_s_setprio(1);
#pragma unroll
    for (int mi = 0; mi < 4; ++mi)
#pragma unroll
      for (int ni = 0; ni < 4; ++ni)
        acc[mi][ni] = MFMA_B16(a[mi], b[ni], acc[mi][ni]);
    __builtin_amdgcn_s_setprio(0);
    __builtin_amdgcn_s_barrier();

    // ---- phase 2: m-half 1, k-slice 0 (reuse b) ----
#pragma unroll
    for (int i = 0; i < 4; ++i)
      a[i] = *(const bf16x8*)(lbase + curB + SWZ(((wm * 128 + (4 + i) * 16 + r) << 6) + kq16));
    STAGE(W, col0, t1 * 64 + 32, nxtB + 49152);  // T(t+1) B s1
    __builtin_amdgcn_s_barrier();
    __builtin_amdgcn_s_setprio(1);
#pragma unroll
    for (int mi = 0; mi < 4; ++mi)
#pragma unroll
      for (int ni = 0; ni < 4; ++ni)
        acc[4 + mi][ni] = MFMA_B16(a[mi], b[ni], acc[4 + mi][ni]);
    __builtin_amdgcn_s_setprio(0);
    __builtin_amdgcn_s_barrier();

    // ---- phase 3: m-half 0, k-slice 1 (s0 regions of buf[cur] now dead) ----
#pragma unroll
    for (int i = 0; i < 4; ++i)
      a[i] = *(const bf16x8*)(lbase + curB + 16384 + SWZ(((wm * 128 + i * 16 + r) << 6) + kq16));
#pragma unroll
    for (int i = 0; i < 4; ++i)
      b[i] = *(const bf16x8*)(lbase + curB + 49152 + SWZ(((wn * 64 + i * 16 + r) << 6) + kq16));
    STAGE(A, row0, t2 * 64, curB);  // T(t+2) A s0 -> dead region
    __builtin_amdgcn_s_barrier();
    __builtin_amdgcn_s_setprio(1);
#pragma unroll
    for (int mi = 0; mi < 4; ++mi)
#pragma unroll
      for (int ni = 0; ni < 4; ++ni)
        acc[mi][ni] = MFMA_B16(a[mi], b[ni], acc[mi][ni]);
    __builtin_amdgcn_s_setprio(0);
    __builtin_amdgcn_s_barrier();

    // ---- phase 4: m-half 1, k-slice 1 (reuse b) ----
#pragma unroll
    for (int i = 0; i < 4; ++i)
      a[i] = *(const bf16x8*)(lbase + curB + 16384 + SWZ(((wm * 128 + (4 + i) * 16 + r) << 6) + kq16));
    STAGE(W, col0, t2 * 64, curB + 32768);  // T(t+2) B s0 -> dead region
    __builtin_amdgcn_s_barrier();
    __builtin_amdgcn_s_setprio(1);
#pragma unroll
    for (int mi = 0; mi < 4; ++mi)
#pragma unroll
      for (int ni = 0; ni < 4; ++ni)
        acc[4 + mi][ni] = MFMA_B16(a[mi], b[ni], acc[4 + mi][ni]);
    __builtin_amdgcn_s_setprio(0);
    // counted wait: <=4 outstanding (= T(t+2) s0 blocks); T(t+1) fully landed
    asm volatile("s_waitcnt vmcnt(4)" ::: "memory");
    __builtin_amdgcn_s_barrier();
  }

  // don't retire with in-flight LDS writes
  asm volatile("s_waitcnt vmcnt(0)" ::: "memory");

  // Epilogue: C/D layout col=lane&15, row=(lane>>4)*4+reg (verified round 1)
  const int kq = kq16 >> 4;
#pragma unroll
  for (int ni = 0; ni < 4; ++ni) {
    const int col = col0 + wn * 64 + ni * 16 + r;
    const float sc = scale[col];
    const float bv = bias[col];
#pragma unroll
    for (int mi = 0; mi < 8; ++mi) {
      const int rowb = row0 + wm * 128 + mi * 16 + kq * 4;
#pragma unroll
      for (int q = 0; q < 4; ++q)
        C[(size_t)(rowb + q) * N_DIM + col] = acc[mi][ni][q] * sc + bv;
    }
  }
}

extern "C" void kernel_launch(void* const* d_in, const int* in_sizes, int n_in,
                              void* d_out, int out_size, void* d_ws, size_t ws_size,
                              hipStream_t stream) {
  const float* x      = (const float*)d_in[0];
  const int*   wq     = (const int*)d_in[1];
  const float* wscale = (const float*)d_in[2];
  const float* wbias  = (const float*)d_in[3];
  float* out = (float*)d_out;

  const size_t xb_bytes = (size_t)M_TOT * K_DIM * 2;   // 32 MB
  const size_t wb_bytes = (size_t)N_DIM * K_DIM * 2;   // 128 MB
  if (ws_size < xb_bytes + wb_bytes) return;

  ushort* xb = (ushort*)d_ws;
  ushort* wb = (ushort*)((char*)d_ws + xb_bytes);

  cvt_f32_bf16_k<<<2048, 256, 0, stream>>>((const float4*)x, (ushort4*)xb,
                                           (M_TOT * K_DIM) / 4);
  cvt_i32_bf16_k<<<2048, 256, 0, stream>>>((const int4*)wq, (ushort4*)wb,
                                           (N_DIM * K_DIM) / 4);

  const int grid = (M_TOT / 256) * (N_DIM / 256);  // 16 * 64 = 1024
  gemm_8phase<<<grid, 512, 0, stream>>>(xb, wb, wscale, wbias, out);
}